// Round 14
// baseline (64.632 us; speedup 1.0000x reference)
//
#include <hip/hip_runtime.h>
#include <hip/hip_bf16.h>
#include <cstdint>
#include <cstddef>

#define A_DIM 128
#define T_DIM 2048
#define F_DIM 128
#define RBF_DIM 16
#define KDD 2048              // K-span per dd block (128 atoms x 16 rbf)
#define VT_LD 18432           // Vt row stride = 9 * KDD
#define NKG 16                // K-groups (A_DIM / 8): halved partial traffic vs R13
#define NA 8                  // atoms per gemm block
#define BT 32                 // t-span per gemm block

typedef __attribute__((ext_vector_type(8))) short short8;
typedef __attribute__((ext_vector_type(4))) float f32x4;
typedef __attribute__((ext_vector_type(4))) unsigned int u32x4;

__device__ __forceinline__ float silu_f(float x) {
    return x / (1.0f + __expf(-x));
}

// f2bf (RNE bit-twiddle) for build_vt; gemm A-build uses v_cvt_pk_bf16_f32
// (also RNE). Do NOT swap for __float2bfloat16.
__device__ __forceinline__ unsigned short f2bf(float x) {
    union { float f; unsigned u; } v; v.f = x;
    unsigned r = v.u + 0x7FFFu + ((v.u >> 16) & 1u);
    return (unsigned short)(r >> 16);
}

// async global->LDS, 16 B per lane; LDS dest is wave-uniform base + lane*16.
__device__ __forceinline__ void gl_lds16(const void* g, void* l) {
    __builtin_amdgcn_global_load_lds(
        (const __attribute__((address_space(1))) void*)g,
        (__attribute__((address_space(3))) void*)l, 16, 0, 0);
}

// Grid-stride float4 zero (fallback path only; plain path zeroes in gemm).
__global__ void zero_kernel(float4* __restrict__ p, int n4) {
    const int stride = gridDim.x * blockDim.x;
    const float4 z = {0.f, 0.f, 0.f, 0.f};
    for (int i = blockIdx.x * blockDim.x + threadIdx.x; i < n4; i += stride)
        p[i] = z;
}

// Fused MLP: layers 1+2 (h2 via LDS) + layer 3 (val[4][4] register tile).
// grid (A/4, 3), block 512. (R13-exact — known good.)
__global__ void mlp_fused_kernel(const float* __restrict__ feat0,
                                 const float* __restrict__ w1, const float* __restrict__ b1,
                                 const float* __restrict__ w2, const float* __restrict__ b2,
                                 const float* __restrict__ w3, const float* __restrict__ b3,
                                 float* __restrict__ rbfws) {
    __shared__ float inv_s[4 * F_DIM];
    __shared__ float h_s[4 * F_DIM];
    __shared__ float h2_s[4 * F_DIM];
    const int i  = blockIdx.y;
    const int a0 = blockIdx.x * 4;
    const int tid = threadIdx.x;
    const int f  = tid & 127;
    const int la = tid >> 7;

    inv_s[tid] = feat0[(a0 + la) * F_DIM + f];
    __syncthreads();

    const float* w1i = w1 + (size_t)i * F_DIM * F_DIM;
    float x = b1[i * F_DIM + f];
    #pragma unroll 8
    for (int k = 0; k < F_DIM; ++k)
        x = fmaf(inv_s[la * F_DIM + k], w1i[k * F_DIM + f], x);
    h_s[tid] = silu_f(x);
    __syncthreads();

    const float* w2i = w2 + (size_t)i * F_DIM * F_DIM;
    float y = b2[i * F_DIM + f];
    #pragma unroll 8
    for (int k = 0; k < F_DIM; ++k)
        y = fmaf(h_s[la * F_DIM + k], w2i[k * F_DIM + f], y);
    h2_s[tid] = silu_f(y);   // tid == la*128 + f
    __syncthreads();

    const int c = tid * 4;
    const float* w3i = w3 + (size_t)i * F_DIM * 2048;
    float val[4][4];
    #pragma unroll
    for (int a = 0; a < 4; ++a) {
        #pragma unroll
        for (int cc = 0; cc < 4; ++cc)
            val[a][cc] = b3[i * 2048 + c + cc];
    }
    for (int k = 0; k < F_DIM; ++k) {
        const float4 w = *reinterpret_cast<const float4*>(&w3i[(size_t)k * 2048 + c]);
        #pragma unroll
        for (int a = 0; a < 4; ++a) {
            const float h = h2_s[a * F_DIM + k];
            val[a][0] = fmaf(h, w.x, val[a][0]);
            val[a][1] = fmaf(h, w.y, val[a][1]);
            val[a][2] = fmaf(h, w.z, val[a][2]);
            val[a][3] = fmaf(h, w.w, val[a][3]);
        }
    }
    const float inv_rbf = 0.25f;  // 1/sqrt(16)
    #pragma unroll
    for (int a = 0; a < 4; ++a) {
        float4 o;
        o.x = val[a][0] * inv_rbf;
        o.y = val[a][1] * inv_rbf;
        o.z = val[a][2] * inv_rbf;
        o.w = val[a][3] * inv_rbf;
        *reinterpret_cast<float4*>(&rbfws[((size_t)i * A_DIM + a0 + a) * 2048 + c]) = o;
    }
}

// Build Vt[f][k] bf16, k = dd*2048 + n*16 + r. (R4-exact.)
__global__ void build_vt_kernel(const float* __restrict__ feat0,
                                const float* __restrict__ feat1,
                                const float* __restrict__ feat2,
                                const float* __restrict__ rbfws,
                                unsigned short* __restrict__ Vt) {
    const int n  = blockIdx.x;
    const int dd = blockIdx.y;
    const int f  = threadIdx.x;

    int i, d;
    float fv;
    if (dd == 0)      { i = 0; d = 0;      fv = feat0[n * F_DIM + f]; }
    else if (dd < 4)  { i = 1; d = dd - 1; fv = feat1[(n * F_DIM + f) * 3 + d]; }
    else              { i = 2; d = dd - 4; fv = feat2[(n * F_DIM + f) * 5 + d]; }

    const float* rb = rbfws + ((size_t)(i * A_DIM + n) * RBF_DIM) * F_DIM + f;
    unsigned short* vp = Vt + (size_t)f * VT_LD + (size_t)dd * KDD + n * 16;
    #pragma unroll
    for (int r = 0; r < RBF_DIM; ++r)
        vp[r] = f2bf(fv * rb[(size_t)r * F_DIM]);
}

// MFMA GEMM — R13 structure with NKG 32->16: 8 atoms/block, BT=32, wave tile
// 16t x 64f (M_rep=1, ks=0..3). Halves partial-buffer HBM traffic (32->16 MB
// written + read). B-tile 128f x 128k = 32 KB LDS, swizzle on low-3 chunk bits
// (rule #21: linear gl_lds dest + pre-swizzled source + swizzled read).
// Monolithic dd-loop — template pipelines failed 3/3 (R5-R7); keep monolithic.
// grid (T/32 = 64, A/8 = 16), block 256 = 4 waves in 2x2.
template<int MODE>
__global__ void __launch_bounds__(256) gemm_kernel(
        const float* __restrict__ sph0, const float* __restrict__ sph1,
        const float* __restrict__ sph2, const float* __restrict__ radial,
        const unsigned short* __restrict__ Vt,
        float* __restrict__ outbuf,
        float* __restrict__ dout, int out_n4) {
    __shared__ unsigned short b_s[F_DIM * 128];  // 32 KB: row f (256 B) x 16 swz chunks
    __shared__ float sph_s[NA * BT];             // 1 KB: [nn][tt]

    const int tid  = threadIdx.x;
    const int lane = tid & 63;
    const int w    = tid >> 6;
    const int wr   = w >> 1;            // wave row (t)
    const int wc   = w & 1;             // wave col (f)
    const int t0   = blockIdx.x * BT + wr * 16;
    const int n0   = blockIdx.y * NA;
    const int kq   = lane >> 4;         // 0..3
    const int lf   = lane & 15;

    // Prologue: zero this block's slice of d_out (plain path only).
    if (MODE == 0) {
        const int bid = blockIdx.y * gridDim.x + blockIdx.x;     // 0..1023
        const float4 z = {0.f, 0.f, 0.f, 0.f};
        float4* zp = (float4*)dout;
        #pragma unroll
        for (int q = 0; q < 8; ++q) {
            const int idx = bid * 2048 + q * 256 + tid;
            if (idx < out_n4) zp[idx] = z;
        }
    }

    // radial is dd-invariant: preload once to regs.
    // k_local = 32*ks + 8*kq + j -> atom n0 + 2*ks + (kq>>1), r = (kq&1)*8 + j.
    f32x4 rad[4][2];
    #pragma unroll
    for (int ks = 0; ks < 4; ++ks) {
        const int n = n0 + 2 * ks + (kq >> 1);
        const int t = t0 + lf;
        const float* rp = radial + ((size_t)n * T_DIM + t) * 16 + (kq & 1) * 8;
        rad[ks][0] = *reinterpret_cast<const f32x4*>(rp);
        rad[ks][1] = *reinterpret_cast<const f32x4*>(rp + 4);
    }

    // B staging source: issue q (0..7) covers rows f = q*16 + tid/16,
    // swizzled chunk c' = tid%16 -> source chunk c = c' ^ ((tid/16)&7).
    const int fs_row = tid >> 4;                  // 0..15 (row within issue)
    const int cs     = (tid & 15) ^ ((tid >> 4) & 7);
    const unsigned short* gsrc0 = Vt + (size_t)fs_row * VT_LD + n0 * 16 + cs * 8;
    // sph staging: thread tid -> sph_s[nn*BT+tt], nn = tid/32, tt = tid%32
    const int nn_s = tid >> 5;
    const int tt_s = tid & 31;
    const size_t sph_tbase = (size_t)(n0 + nn_s) * T_DIM + blockIdx.x * BT + tt_s;

    f32x4 acc[4];
    #pragma unroll
    for (int nf = 0; nf < 4; ++nf)
        acc[nf] = (f32x4){0.f, 0.f, 0.f, 0.f};

    #pragma unroll 1
    for (int dd = 0; dd < 9; ++dd) {
        const float* sp; int smul, soff;
        if (dd == 0)     { sp = sph0; smul = 1; soff = 0; }
        else if (dd < 4) { sp = sph1; smul = 3; soff = dd - 1; }
        else             { sp = sph2; smul = 5; soff = dd - 4; }

        __syncthreads();   // previous iteration done reading LDS

        // stage B-tile: 8 issues x (256 lanes x 16 B) = 32 KB, linear LDS dest
        const size_t koff = (size_t)dd * KDD;
        #pragma unroll
        for (int q = 0; q < 8; ++q) {
            const unsigned short* gp = gsrc0 + koff + (size_t)(q * 16) * VT_LD;
            void* lp = (void*)((char*)b_s + q * 4096 + w * 1024);
            gl_lds16(gp, lp);
        }
        // stage sph tile (256 floats)
        sph_s[tid] = sp[sph_tbase * smul + soff];

        __syncthreads();   // drains vmcnt+lgkmcnt before s_barrier

        // Per k-slice: B-frags from LDS (swizzled), A-frag via cvt_pk, 4 MFMAs.
        #pragma unroll
        for (int ks = 0; ks < 4; ++ks) {
            short8 bfr[4];
            #pragma unroll
            for (int nf = 0; nf < 4; ++nf) {
                const int f = wc * 64 + 16 * nf + lf;
                const int byte = f * 256 + (((ks * 4 + kq) ^ (lf & 7)) * 16);
                bfr[nf] = *reinterpret_cast<const short8*>((const char*)b_s + byte);
            }
            const float s = sph_s[(2 * ks + (kq >> 1)) * BT + wr * 16 + lf];
            unsigned int d0, d1, d2, d3;
            asm("v_cvt_pk_bf16_f32 %0, %1, %2" : "=v"(d0)
                : "v"(s * rad[ks][0][0]), "v"(s * rad[ks][0][1]));
            asm("v_cvt_pk_bf16_f32 %0, %1, %2" : "=v"(d1)
                : "v"(s * rad[ks][0][2]), "v"(s * rad[ks][0][3]));
            asm("v_cvt_pk_bf16_f32 %0, %1, %2" : "=v"(d2)
                : "v"(s * rad[ks][1][0]), "v"(s * rad[ks][1][1]));
            asm("v_cvt_pk_bf16_f32 %0, %1, %2" : "=v"(d3)
                : "v"(s * rad[ks][1][2]), "v"(s * rad[ks][1][3]));
            union { u32x4 u; short8 s8; } au;
            au.u = (u32x4){d0, d1, d2, d3};
            #pragma unroll
            for (int nf = 0; nf < 4; ++nf)
                acc[nf] = __builtin_amdgcn_mfma_f32_16x16x32_bf16(
                    au.s8, bfr[nf], acc[nf], 0, 0, 0);
        }
    }

    // Epilogue. C/D layout col=lane&15, row=(lane>>4)*4+reg (HW-verified in R4).
    float* pb = (MODE == 0)
        ? outbuf + (size_t)blockIdx.y * (T_DIM * F_DIM)   // own slice, plain stores
        : outbuf;                                          // shared, atomics
    #pragma unroll
    for (int nf = 0; nf < 4; ++nf) {
        const int f = wc * 64 + 16 * nf + lf;
        #pragma unroll
        for (int reg = 0; reg < 4; ++reg) {
            const int t = t0 + 4 * kq + reg;
            if (MODE == 0)
                pb[(size_t)t * F_DIM + f] = acc[nf][reg];
            else
                atomicAdd(&pb[(size_t)t * F_DIM + f], acc[nf][reg]);
        }
    }
}

// Plain path: sum NKG partial slices, then indexed atomicAdd into out.
__global__ void scatter_sum_kernel(const float* __restrict__ partial,
                                   const int* __restrict__ tidx,
                                   float* __restrict__ out) {
    const int tid = threadIdx.x;
    const int t = blockIdx.x * 2 + (tid >> 7);
    const int f = tid & 127;
    const int g = tidx[t];
    const float* p = partial + (size_t)t * F_DIM + f;
    float s = 0.0f;
    #pragma unroll
    for (int kg = 0; kg < NKG; ++kg)
        s += p[(size_t)kg * (T_DIM * F_DIM)];
    atomicAdd(&out[(size_t)g * F_DIM + f], s);
}

// Fallback path: scatter sparse rows into d_out.
__global__ void scatter_kernel(const float* __restrict__ sparse,
                               const int* __restrict__ tidx,
                               float* __restrict__ out) {
    const int tid = threadIdx.x;
    const int t = blockIdx.x * 2 + (tid >> 7);
    const int f = tid & 127;
    const int g = tidx[t];
    atomicAdd(&out[(size_t)g * F_DIM + f], sparse[(size_t)t * F_DIM + f]);
}

extern "C" void kernel_launch(void* const* d_in, const int* in_sizes, int n_in,
                              void* d_out, int out_size, void* d_ws, size_t ws_size,
                              hipStream_t stream) {
    const float* feat0  = (const float*)d_in[0];
    const float* feat1  = (const float*)d_in[1];
    const float* feat2  = (const float*)d_in[2];
    const float* sph0   = (const float*)d_in[3];
    const float* sph1   = (const float*)d_in[4];
    const float* sph2   = (const float*)d_in[5];
    const float* radial = (const float*)d_in[6];
    const float* w1     = (const float*)d_in[7];
    const float* b1     = (const float*)d_in[8];
    const float* w2     = (const float*)d_in[9];
    const float* b2     = (const float*)d_in[10];
    const float* w3     = (const float*)d_in[11];
    const float* b3     = (const float*)d_in[12];
    const int*   tidx   = (const int*)d_in[13];
    float* out = (float*)d_out;

    // Common ws prefix: rbfws 3 MB | h2ws slot kept for layout stability
    float* rbfws  = (float*)d_ws;
    float* h2ws   = rbfws + 3 * A_DIM * RBF_DIM * F_DIM;

    // Plain path needs: prefix + Vt (4.5 MB) + partial (16 MB) ~= 25.7 MB
    const size_t plain_need =
        (size_t)(3 * A_DIM * RBF_DIM * F_DIM + 3 * A_DIM * F_DIM) * sizeof(float) +
        (size_t)F_DIM * VT_LD * sizeof(unsigned short) +
        (size_t)NKG * T_DIM * F_DIM * sizeof(float);
    const bool plain = (ws_size >= plain_need);

    mlp_fused_kernel<<<dim3(A_DIM / 4, 3), 512, 0, stream>>>(
        feat0, w1, b1, w2, b2, w3, b3, rbfws);

    if (plain) {
        unsigned short* Vt = (unsigned short*)(h2ws + 3 * A_DIM * F_DIM);
        float* partial = (float*)(Vt + (size_t)F_DIM * VT_LD);
        build_vt_kernel<<<dim3(A_DIM, 9), 128, 0, stream>>>(feat0, feat1, feat2, rbfws, Vt);
        gemm_kernel<0><<<dim3(T_DIM / BT, A_DIM / NA), 256, 0, stream>>>(
            sph0, sph1, sph2, radial, Vt, partial, out, out_size / 4);
        scatter_sum_kernel<<<dim3(T_DIM / 2), 256, 0, stream>>>(partial, tidx, out);
    } else {
        // Fallback layout: rbfws | h2ws | sparse | Vt
        float* sparse = h2ws + 3 * A_DIM * F_DIM;
        unsigned short* Vt = (unsigned short*)(sparse + T_DIM * F_DIM);
        zero_kernel<<<2048, 256, 0, stream>>>((float4*)out, out_size / 4);
        hipMemsetAsync(sparse, 0, (size_t)T_DIM * F_DIM * sizeof(float), stream);
        build_vt_kernel<<<dim3(A_DIM, 9), 128, 0, stream>>>(feat0, feat1, feat2, rbfws, Vt);
        gemm_kernel<1><<<dim3(T_DIM / BT, A_DIM / NA), 256, 0, stream>>>(
            sph0, sph1, sph2, radial, Vt, sparse, out, out_size / 4);
        scatter_kernel<<<dim3(T_DIM / 2), 256, 0, stream>>>(sparse, tidx, out);
    }
}